// Round 9
// baseline (7164.060 us; speedup 1.0000x reference)
//
#include <hip/hip_runtime.h>
#include <math.h>

#define T_SEQ 1024
#define B_SZ  128
#define I_SZ  256
#define H_SZ  512
#define G_SZ  1536  // 3*H

#define NBS   8     // batch slices (clusters)
#define MB    16    // batch per block
#define NHS   4     // h slices = blocks per cluster
#define HB    128   // h cols per block
#define GB    384   // gate cols per block (3*HB)
#define NTHR  512   // 8 waves
#define PGB   384   // proj: gate cols per block
#define INBOX (MB * H_SZ)   // 8192 f16 = 16 KB per parity per block

#define SENT32 0x7FFF7FFFu  // two f16 NaNs; h clipped to +-5 so never legit

typedef _Float16 f16;
typedef _Float16 half8 __attribute__((ext_vector_type(8)));
typedef _Float16 f16x4 __attribute__((ext_vector_type(4)));
typedef float f32x4 __attribute__((ext_vector_type(4)));
typedef unsigned uint32x4 __attribute__((ext_vector_type(4)));

// ---- MALL-coherent (sc0 sc1) ops: bypass L1/L2; device-wide coherent ----
__device__ __forceinline__ f32x4 cload_f4(const void* p) {
    f32x4 v;
    asm volatile("global_load_dwordx4 %0, %1, off sc0 sc1" : "=v"(v) : "v"(p));
    return v;
}
__device__ __forceinline__ void cstore_f4(void* p, f32x4 v) {
    asm volatile("global_store_dwordx4 %0, %1, off sc0 sc1" :: "v"(p), "v"(v) : "memory");
}
__device__ __forceinline__ f16x4 load_f16x4_nw(const void* p) {
    f16x4 v;
    asm volatile("global_load_dwordx2 %0, %1, off" : "=v"(v) : "v"(p));
    return v;
}
__device__ __forceinline__ void wait_vm0() {
    asm volatile("s_waitcnt vmcnt(0)" ::: "memory");
    __builtin_amdgcn_sched_barrier(0);
}
__device__ __forceinline__ bool stale4(f32x4 v) {
    uint32x4 u = __builtin_bit_cast(uint32x4, v);
    return (u[0] == SENT32) | (u[1] == SENT32) | (u[2] == SENT32) | (u[3] == SENT32);
}

// ---------------------------------------------------------------------------
// Setup: w_ih -> f16 [g][i]; w_hh -> f16 slices [hs=4][GB=384][512]
// (k-contiguous); hbox parity0 <- h0 broadcast, parity1 <- sentinel.
// ---------------------------------------------------------------------------
__global__ void setup_kernel(const float* __restrict__ w_ih,
                             const float* __restrict__ w_hh,
                             const float* __restrict__ h0,
                             f16* __restrict__ wp16,
                             f16* __restrict__ wf16,
                             f16* __restrict__ hbox) {
    const int i0 = blockIdx.x * blockDim.x + threadIdx.x;
    const int stride = gridDim.x * blockDim.x;
    for (int i = i0; i < I_SZ * G_SZ; i += stride)
        wp16[i] = (f16)w_ih[i];
    for (int i = i0; i < NHS * GB * H_SZ; i += stride) {
        int hs  = i / (GB * H_SZ);
        int rem = i % (GB * H_SZ);
        int gl = rem / H_SZ, k = rem % H_SZ;
        int gate = gl >> 7, c = gl & 127;
        int gg = gate * H_SZ + hs * HB + c;
        wf16[i] = (f16)w_hh[(size_t)gg * H_SZ + k];
    }
    const int htot = 2 * NBS * NHS * INBOX;   // 524288
    const int half = htot / 2;
    const f16 sent = __builtin_bit_cast(f16, (unsigned short)0x7FFF);
    for (int i = i0; i < htot; i += stride) {
        if (i < half) hbox[i] = (f16)h0[i & (H_SZ - 1)];
        else          hbox[i] = sent;
    }
}

// ---------------------------------------------------------------------------
// Input projection, f16 MFMA (validated R4-R7, unchanged). Dense gi layout:
// gi16[((t*NBS + bs)*G + g)*MB + m],  bs = b>>4, m = b&15.
// ---------------------------------------------------------------------------
__global__ __launch_bounds__(512, 1)
void proj_kernel(const float* __restrict__ x,
                 const f16* __restrict__ wp16,
                 const float* __restrict__ b_ih,
                 f16* __restrict__ gi16) {
    const int t  = blockIdx.x >> 2;
    const int g0 = (blockIdx.x & 3) * PGB;
    const int tid  = threadIdx.x;
    const int wid  = tid >> 6;
    const int lane = tid & 63;
    const int col  = lane & 15;
    const int krow = lane >> 4;

    __shared__ __align__(16) unsigned char x_lds[128 * 512];  // [b][k] f16, 64 KB

    #pragma unroll
    for (int j = 0; j < 8; ++j) {
        int idx = tid + j * 512;
        int b = idx >> 5, k16 = idx & 31;
        const float* xp = x + ((size_t)b * T_SEQ + t) * I_SZ + k16 * 8;
        float4 v0 = *reinterpret_cast<const float4*>(xp);
        float4 v1 = *reinterpret_cast<const float4*>(xp + 4);
        half8 hv;
        hv[0] = (f16)v0.x; hv[1] = (f16)v0.y; hv[2] = (f16)v0.z; hv[3] = (f16)v0.w;
        hv[4] = (f16)v1.x; hv[5] = (f16)v1.y; hv[6] = (f16)v1.z; hv[7] = (f16)v1.w;
        unsigned addr = ((unsigned)(b * 512 + k16 * 16)) ^ (((unsigned)(b & 7)) << 4);
        *reinterpret_cast<half8*>(x_lds + addr) = hv;
    }

    const int gw0 = g0 + wid * 48;
    half8 af[3][8];
    #pragma unroll
    for (int m = 0; m < 3; ++m)
        #pragma unroll
        for (int k = 0; k < 8; ++k)
            af[m][k] = *reinterpret_cast<const half8*>(
                wp16 + (size_t)(gw0 + m * 16 + col) * I_SZ + k * 32 + krow * 8);

    float bias[3][4];
    #pragma unroll
    for (int m = 0; m < 3; ++m)
        #pragma unroll
        for (int r = 0; r < 4; ++r)
            bias[m][r] = b_ih[gw0 + m * 16 + krow * 4 + r];

    __syncthreads();

    #pragma unroll
    for (int nt = 0; nt < 8; ++nt) {
        const int b0 = nt * 16;
        f32x4 acc0 = {0.f,0.f,0.f,0.f}, acc1 = {0.f,0.f,0.f,0.f}, acc2 = {0.f,0.f,0.f,0.f};
        const int brow = b0 + col;
        const unsigned bswz = ((unsigned)(brow & 7)) << 4;
        #pragma unroll
        for (int k = 0; k < 8; ++k) {
            half8 bf = *reinterpret_cast<const half8*>(
                x_lds + (((unsigned)(brow * 512 + k * 64 + krow * 16)) ^ bswz));
            acc0 = __builtin_amdgcn_mfma_f32_16x16x32_f16(af[0][k], bf, acc0, 0, 0, 0);
            acc1 = __builtin_amdgcn_mfma_f32_16x16x32_f16(af[1][k], bf, acc1, 0, 0, 0);
            acc2 = __builtin_amdgcn_mfma_f32_16x16x32_f16(af[2][k], bf, acc2, 0, 0, 0);
        }
        const int pbs = brow >> 4;
        const int pm  = brow & 15;
        #pragma unroll
        for (int r = 0; r < 4; ++r) {
            int gr = gw0 + krow * 4 + r;
            gi16[((size_t)(t * NBS + pbs) * G_SZ + gr)      * MB + pm] = (f16)(acc0[r] + bias[0][r]);
            gi16[((size_t)(t * NBS + pbs) * G_SZ + gr + 16) * MB + pm] = (f16)(acc1[r] + bias[1][r]);
            gi16[((size_t)(t * NBS + pbs) * G_SZ + gr + 32) * MB + pm] = (f16)(acc2[r] + bias[2][r]);
        }
    }
}

// ---------------------------------------------------------------------------
// Persistent GRU, R7-validated flagless push protocol at fan-out 4.
// 32 blocks = 8 clusters x 4 h-slices; block owns 128 h-cols (24 MFMA tiles,
// 3 per wave). Tiles 0,1: persistent plain-load B-fragments (128 VGPR,
// budget 512 via launch_bounds(512,1) -> no remat). Tile 2: streamed from
// L2 each step (plain loads, address-stable -> L2-hot, hidden under MFMA).
// ---------------------------------------------------------------------------
__global__ __launch_bounds__(NTHR, 1)
void gru_persist(const f16* __restrict__ gi,      // [T][NBS][G][MB] f16
                 const f16* __restrict__ wf16,    // [NHS][GB][512]
                 const float* __restrict__ h0,
                 const float* __restrict__ b_hh,
                 f16* __restrict__ hbox,          // [2][NBS][NHS][MB][512]
                 float* __restrict__ out) {
    const int bs  = blockIdx.x & (NBS - 1);
    const int hs  = blockIdx.x >> 3;   // 0..3
    const int tid = threadIdx.x;

    __shared__ __align__(16) unsigned char h_lds[MB * H_SZ * 2];  // 16 KB
    __shared__ float pre[3][MB][HB + 1];   // r,z: pre+gi; n: pre only
    __shared__ float inn[MB][HB + 1];      // gi for n gate
    __shared__ float hmast[MB][HB + 1];    // f32 running h

    const int wid  = tid >> 6;
    const int lane = tid & 63;
    const int col  = lane & 15;
    const int krow = lane >> 4;

    // tiles tt = wid*3 + mt, tt in [0,24): gate = tt>>3, col-tile = (tt&7)*16
    int tgate[3], tcol[3];
    float tbias[3];
    #pragma unroll
    for (int mt = 0; mt < 3; ++mt) {
        int tt = wid * 3 + mt;
        tgate[mt] = tt >> 3;
        tcol[mt]  = (tt & 7) * 16 + col;   // 0..127
        tbias[mt] = b_hh[tgate[mt] * H_SZ + hs * HB + tcol[mt]];
    }

    // persistent B fragments, tiles 0 and 1 (plain loads; stays resident)
    const f16* wsl = wf16 + (size_t)hs * GB * H_SZ;
    half8 bf0[16], bf1[16];
    {
        const f16* w0 = wsl + (size_t)(tgate[0] * HB + tcol[0]) * H_SZ + krow * 8;
        const f16* w1 = wsl + (size_t)(tgate[1] * HB + tcol[1]) * H_SZ + krow * 8;
        #pragma unroll
        for (int kk = 0; kk < 16; ++kk) {
            bf0[kk] = *reinterpret_cast<const half8*>(w0 + kk * 32);
            bf1[kk] = *reinterpret_cast<const half8*>(w1 + kk * 32);
        }
    }
    // tile 2 streamed per step from here (L2-hot)
    const f16* w2 = wsl + (size_t)(tgate[2] * HB + tcol[2]) * H_SZ + krow * 8;

    // f32 h master in LDS
    for (int i = tid; i < MB * HB; i += NTHR)
        hmast[i >> 7][i & 127] = h0[hs * HB + (i & 127)];
    __syncthreads();

    const unsigned a_base = (unsigned)(col * 1024 + krow * 16);
    const unsigned a_swz  = ((unsigned)(col & 7)) << 4;

    // inbox granules: 2 x 16B per thread (1024 granules of 16B = 16 KB)
    const int i0 = tid, i1 = tid + NTHR;
    const f32x4 sentv = __builtin_bit_cast(f32x4,
        (uint32x4){SENT32, SENT32, SENT32, SENT32});

    // combine ownership (tid<256): batch cbb, 8 cols from cc8
    const int cbb = tid >> 4;
    const int cc8 = (tid & 15) * 8;

    for (int t = 0; t < T_SEQ; ++t) {
        const int p  = t & 1;
        const int p1 = p ^ 1;
        f16* mybox = hbox + ((size_t)(p * NBS + bs) * NHS + hs) * INBOX;
        f16* a0p = mybox + (i0 >> 6) * H_SZ + (i0 & 63) * 8;
        f16* a1p = mybox + (i1 >> 6) * H_SZ + (i1 & 63) * 8;

        // gi loads issued first; drain folds into the first poll wait
        f16x4 gv[3];
        #pragma unroll
        for (int mt = 0; mt < 3; ++mt)
            gv[mt] = load_f16x4_nw(
                gi + ((size_t)(t * NBS + bs) * G_SZ
                      + tgate[mt] * H_SZ + hs * HB + tcol[mt]) * MB + krow * 4);

        // ---- poll inbox until sentinel-free ----
        f32x4 v0 = cload_f4(a0p);
        f32x4 v1 = cload_f4(a1p);
        wait_vm0();
        {
            int guard = 0;
            bool s0 = stale4(v0), s1 = stale4(v1);
            while (__any(s0 | s1)) {
                if (s0) v0 = cload_f4(a0p);
                if (s1) v1 = cload_f4(a1p);
                wait_vm0();
                s0 = stale4(v0); s1 = stale4(v1);
                if (++guard > (1 << 17)) break;   // safety valve
            }
        }

        // ---- stage to LDS (swizzled) + re-arm sentinel (fire-and-forget) ----
        {
            unsigned b0r = (unsigned)(i0 >> 6), b1r = (unsigned)(i1 >> 6);
            unsigned l0 = (b0r * 1024 + (i0 & 63) * 16) ^ ((b0r & 7) << 4);
            unsigned l1 = (b1r * 1024 + (i1 & 63) * 16) ^ ((b1r & 7) << 4);
            *reinterpret_cast<f32x4*>(h_lds + l0) = v0;
            *reinterpret_cast<f32x4*>(h_lds + l1) = v1;
            cstore_f4(a0p, sentv);
            cstore_f4(a1p, sentv);
        }
        __syncthreads();

        // ---- gh: 16 batch x 48 cols, K=512; tile2 weights streamed ----
        f32x4 acc0 = {0.f,0.f,0.f,0.f}, acc1 = {0.f,0.f,0.f,0.f}, acc2 = {0.f,0.f,0.f,0.f};
        #pragma unroll
        for (int kk = 0; kk < 16; ++kk) {
            half8 av = *reinterpret_cast<const half8*>(
                h_lds + ((a_base + kk * 64) ^ a_swz));
            half8 w2f = *reinterpret_cast<const half8*>(w2 + kk * 32);
            acc0 = __builtin_amdgcn_mfma_f32_16x16x32_f16(av, bf0[kk], acc0, 0, 0, 0);
            acc1 = __builtin_amdgcn_mfma_f32_16x16x32_f16(av, bf1[kk], acc1, 0, 0, 0);
            acc2 = __builtin_amdgcn_mfma_f32_16x16x32_f16(av, w2f,     acc2, 0, 0, 0);
        }
        wait_vm0();   // re-arm stores acked (hidden under MFMA) [protocol-critical]

        // ---- pre-activation to LDS ----
        #pragma unroll
        for (int mt = 0; mt < 3; ++mt) {
            f32x4 a = (mt == 0) ? acc0 : (mt == 1) ? acc1 : acc2;
            if (tgate[mt] < 2) {
                #pragma unroll
                for (int r = 0; r < 4; ++r)
                    pre[tgate[mt]][krow * 4 + r][tcol[mt]] =
                        a[r] + tbias[mt] + (float)gv[mt][r];
            } else {
                #pragma unroll
                for (int r = 0; r < 4; ++r) {
                    pre[2][krow * 4 + r][tcol[mt]] = a[r] + tbias[mt];
                    inn[krow * 4 + r][tcol[mt]]    = (float)gv[mt][r];
                }
            }
        }
        __syncthreads();

        // ---- combine (tid<256): 1 batch x 8 cols; push 16B to 4 peers ----
        if (tid < 256) {
            float h8[8];
            half8 pk;
            #pragma unroll
            for (int u = 0; u < 8; ++u) {
                int c = cc8 + u;
                float r = 1.f / (1.f + __expf(-pre[0][cbb][c]));
                float z = 1.f / (1.f + __expf(-pre[1][cbb][c]));
                float a = inn[cbb][c] + r * pre[2][cbb][c];
                float n = 1.f - 2.f / (__expf(2.f * a) + 1.f);
                float hn = (1.f - z) * n + z * hmast[cbb][c];
                hn = fminf(fmaxf(hn, -5.f), 5.f);
                hmast[cbb][c] = hn;
                h8[u] = hn;
                pk[u] = (f16)hn;
            }
            f32x4 pkv = __builtin_bit_cast(f32x4, pk);
            f16* base = hbox + ((size_t)(p1 * NBS + bs) * NHS) * INBOX
                             + (size_t)cbb * H_SZ + hs * HB + cc8;
            #pragma unroll
            for (int j = 0; j < NHS; ++j)
                cstore_f4(base + (size_t)j * INBOX, pkv);

            const int bg = bs * MB + cbb;
            const int hg = hs * HB + cc8;
            float4 o0 = make_float4(h8[0], h8[1], h8[2], h8[3]);
            float4 o1 = make_float4(h8[4], h8[5], h8[6], h8[7]);
            *reinterpret_cast<float4*>(out + ((size_t)bg * T_SEQ + t) * H_SZ + hg)     = o0;
            *reinterpret_cast<float4*>(out + ((size_t)bg * T_SEQ + t) * H_SZ + hg + 4) = o1;
            if (t == T_SEQ - 1) {
                size_t tail = (size_t)B_SZ * T_SEQ * H_SZ;
                *reinterpret_cast<float4*>(out + tail + (size_t)bg * H_SZ + hg)     = o0;
                *reinterpret_cast<float4*>(out + tail + (size_t)bg * H_SZ + hg + 4) = o1;
            }
        }
        // no drain, no flag, no barrier: next step's poll is the sync.
    }
}

// ---------------------------------------------------------------------------
extern "C" void kernel_launch(void* const* d_in, const int* in_sizes, int n_in,
                              void* d_out, int out_size, void* d_ws, size_t ws_size,
                              hipStream_t stream) {
    const float* x    = (const float*)d_in[0];
    const float* h0   = (const float*)d_in[1];
    const float* w_ih = (const float*)d_in[2];
    const float* w_hh = (const float*)d_in[3];
    const float* b_ih = (const float*)d_in[4];
    const float* b_hh = (const float*)d_in[5];
    float* out = (float*)d_out;

    char* p = (char*)d_ws;
    f16* wp16 = (f16*)p;   p += (size_t)I_SZ * G_SZ * 2;               // 768 KB
    f16* wf16 = (f16*)p;   p += (size_t)NHS * GB * H_SZ * 2;           // 1.5 MB
    f16* hbox = (f16*)p;   p += (size_t)2 * NBS * NHS * INBOX * 2;     // 1 MB
    f16* gi   = (f16*)p;   // [T][NBS][G][MB] f16 = 402 MB (ws >= 810 MB proven)

    setup_kernel<<<512, 256, 0, stream>>>(w_ih, w_hh, h0, wp16, wf16, hbox);

    proj_kernel<<<T_SEQ * 4, 512, 0, stream>>>(x, wp16, b_ih, gi);

    gru_persist<<<NBS * NHS, NTHR, 0, stream>>>(gi, wf16, h0, b_hh, hbox, out);
}

// Round 10
// 3352.756 us; speedup vs baseline: 2.1368x; 2.1368x over previous
//
#include <hip/hip_runtime.h>
#include <math.h>

#define T_SEQ 1024
#define B_SZ  128
#define I_SZ  256
#define H_SZ  512
#define G_SZ  1536  // 3*H

#define NBS   8     // batch slices (clusters)
#define MB    16    // batch per block
#define NHS   16    // h slices = blocks per cluster
#define HB    32    // h cols per block
#define GB    96    // gate cols per block (3*HB)
#define NTHR  384   // 6 waves
#define PGB   384   // proj: gate cols per block

#define SENT32 0x7FFF7FFFu  // two f16 NaNs; h clipped to +-5 so never legit

typedef _Float16 f16;
typedef _Float16 half8 __attribute__((ext_vector_type(8)));
typedef _Float16 f16x4 __attribute__((ext_vector_type(4)));
typedef float f32x4 __attribute__((ext_vector_type(4)));
typedef unsigned uint32x4 __attribute__((ext_vector_type(4)));

// ---- MALL-coherent (sc0 sc1) ops: bypass L1/L2; device-wide coherent ----
__device__ __forceinline__ f32x4 cload_f4(const void* p) {
    f32x4 v;
    asm volatile("global_load_dwordx4 %0, %1, off sc0 sc1" : "=v"(v) : "v"(p));
    return v;
}
__device__ __forceinline__ void cstore_f4(void* p, f32x4 v) {
    asm volatile("global_store_dwordx4 %0, %1, off sc0 sc1" :: "v"(p), "v"(v) : "memory");
}
__device__ __forceinline__ void cstore_u32(void* p, unsigned v) {
    asm volatile("global_store_dword %0, %1, off sc0 sc1" :: "v"(p), "v"(v) : "memory");
}
__device__ __forceinline__ f16x4 load_f16x4_nw(const void* p) {
    f16x4 v;
    asm volatile("global_load_dwordx2 %0, %1, off" : "=v"(v) : "v"(p));
    return v;
}
__device__ __forceinline__ void wait_vm0() {
    asm volatile("s_waitcnt vmcnt(0)" ::: "memory");
    __builtin_amdgcn_sched_barrier(0);
}
__device__ __forceinline__ bool stale4(f32x4 v) {
    uint32x4 u = __builtin_bit_cast(uint32x4, v);
    return (u[0] == SENT32) | (u[1] == SENT32) | (u[2] == SENT32) | (u[3] == SENT32);
}

// ---------------------------------------------------------------------------
// Setup: w_ih -> f16 [g][i]; w_hh -> f16 slices [hs=16][GB=96][512]
// (k-contiguous per gate-col); hbuf phase0 <- h0 broadcast, phases 1,2 <-
// sentinel.
// ---------------------------------------------------------------------------
__global__ void setup_kernel(const float* __restrict__ w_ih,
                             const float* __restrict__ w_hh,
                             const float* __restrict__ h0,
                             f16* __restrict__ wp16,
                             f16* __restrict__ wf16,
                             f16* __restrict__ hbuf) {
    const int i0 = blockIdx.x * blockDim.x + threadIdx.x;
    const int stride = gridDim.x * blockDim.x;
    for (int i = i0; i < I_SZ * G_SZ; i += stride)
        wp16[i] = (f16)w_ih[i];
    for (int i = i0; i < NHS * GB * H_SZ; i += stride) {
        int hs  = i / (GB * H_SZ);
        int rem = i % (GB * H_SZ);
        int gl = rem / H_SZ, k = rem % H_SZ;
        int gate = gl >> 5, c = gl & 31;
        int gg = gate * H_SZ + hs * HB + c;
        wf16[i] = (f16)w_hh[(size_t)gg * H_SZ + k];
    }
    const int hph = B_SZ * H_SZ;           // one phase: 65536 f16
    const f16 sent = __builtin_bit_cast(f16, (unsigned short)0x7FFF);
    for (int i = i0; i < 3 * hph; i += stride) {
        if (i < hph) hbuf[i] = (f16)h0[i & (H_SZ - 1)];
        else         hbuf[i] = sent;
    }
}

// ---------------------------------------------------------------------------
// Input projection, f16 MFMA (passed R7/R9 unchanged). Dense gi layout:
// gi16[((t*NBS + bs)*G + g)*MB + m],  bs = b>>4, m = b&15.
// ---------------------------------------------------------------------------
__global__ __launch_bounds__(512, 1)
void proj_kernel(const float* __restrict__ x,
                 const f16* __restrict__ wp16,
                 const float* __restrict__ b_ih,
                 f16* __restrict__ gi16) {
    const int t  = blockIdx.x >> 2;
    const int g0 = (blockIdx.x & 3) * PGB;
    const int tid  = threadIdx.x;
    const int wid  = tid >> 6;
    const int lane = tid & 63;
    const int col  = lane & 15;
    const int krow = lane >> 4;

    __shared__ __align__(16) unsigned char x_lds[128 * 512];  // [b][k] f16, 64 KB

    #pragma unroll
    for (int j = 0; j < 8; ++j) {
        int idx = tid + j * 512;
        int b = idx >> 5, k16 = idx & 31;
        const float* xp = x + ((size_t)b * T_SEQ + t) * I_SZ + k16 * 8;
        float4 v0 = *reinterpret_cast<const float4*>(xp);
        float4 v1 = *reinterpret_cast<const float4*>(xp + 4);
        half8 hv;
        hv[0] = (f16)v0.x; hv[1] = (f16)v0.y; hv[2] = (f16)v0.z; hv[3] = (f16)v0.w;
        hv[4] = (f16)v1.x; hv[5] = (f16)v1.y; hv[6] = (f16)v1.z; hv[7] = (f16)v1.w;
        unsigned addr = ((unsigned)(b * 512 + k16 * 16)) ^ (((unsigned)(b & 7)) << 4);
        *reinterpret_cast<half8*>(x_lds + addr) = hv;
    }

    const int gw0 = g0 + wid * 48;
    half8 af[3][8];
    #pragma unroll
    for (int m = 0; m < 3; ++m)
        #pragma unroll
        for (int k = 0; k < 8; ++k)
            af[m][k] = *reinterpret_cast<const half8*>(
                wp16 + (size_t)(gw0 + m * 16 + col) * I_SZ + k * 32 + krow * 8);

    float bias[3][4];
    #pragma unroll
    for (int m = 0; m < 3; ++m)
        #pragma unroll
        for (int r = 0; r < 4; ++r)
            bias[m][r] = b_ih[gw0 + m * 16 + krow * 4 + r];

    __syncthreads();

    #pragma unroll
    for (int nt = 0; nt < 8; ++nt) {
        const int b0 = nt * 16;
        f32x4 acc0 = {0.f,0.f,0.f,0.f}, acc1 = {0.f,0.f,0.f,0.f}, acc2 = {0.f,0.f,0.f,0.f};
        const int brow = b0 + col;
        const unsigned bswz = ((unsigned)(brow & 7)) << 4;
        #pragma unroll
        for (int k = 0; k < 8; ++k) {
            half8 bf = *reinterpret_cast<const half8*>(
                x_lds + (((unsigned)(brow * 512 + k * 64 + krow * 16)) ^ bswz));
            acc0 = __builtin_amdgcn_mfma_f32_16x16x32_f16(af[0][k], bf, acc0, 0, 0, 0);
            acc1 = __builtin_amdgcn_mfma_f32_16x16x32_f16(af[1][k], bf, acc1, 0, 0, 0);
            acc2 = __builtin_amdgcn_mfma_f32_16x16x32_f16(af[2][k], bf, acc2, 0, 0, 0);
        }
        const int pbs = brow >> 4;
        const int pm  = brow & 15;
        #pragma unroll
        for (int r = 0; r < 4; ++r) {
            int gr = gw0 + krow * 4 + r;
            gi16[((size_t)(t * NBS + pbs) * G_SZ + gr)      * MB + pm] = (f16)(acc0[r] + bias[0][r]);
            gi16[((size_t)(t * NBS + pbs) * G_SZ + gr + 16) * MB + pm] = (f16)(acc1[r] + bias[1][r]);
            gi16[((size_t)(t * NBS + pbs) * G_SZ + gr + 32) * MB + pm] = (f16)(acc2[r] + bias[2][r]);
        }
    }
}

// ---------------------------------------------------------------------------
// Persistent GRU: R5 geometry (128 blocks = 8 clusters x 16 h-slices, 384 thr,
// 64-VGPR resident B-fragments) + 3-phase sentinel-pull exchange:
//   step t: poll hbuf[t%3] data granules directly (sentinel = f16 NaN pair),
//           arm own granules of hbuf[(t+2)%3] (consumed by all, proven by the
//           poll success), combine writes h once to hbuf[(t+1)%3].
// No flags, no store-drain, no end-of-step barrier: 1 MALL RT per step.
// ---------------------------------------------------------------------------
__global__ __launch_bounds__(NTHR, 1)
void gru_persist(const f16* __restrict__ gi,      // [T][NBS][G][MB] f16
                 const f16* __restrict__ wf16,    // [NHS][GB][512]
                 const float* __restrict__ h0,
                 const float* __restrict__ b_hh,
                 f16* __restrict__ hbuf,          // [3][B][H] f16
                 float* __restrict__ out) {
    const int bs  = blockIdx.x & (NBS - 1);
    const int hs  = blockIdx.x >> 3;   // 0..15
    const int tid = threadIdx.x;

    __shared__ __align__(16) unsigned char h_lds[MB * H_SZ * 2];  // 16 KB
    __shared__ float act_r[MB][HB + 1];
    __shared__ float act_z[MB][HB + 1];
    __shared__ float act_n[MB][HB + 1];
    __shared__ float act_i[MB][HB + 1];

    const int wid  = tid >> 6;
    const int lane = tid & 63;
    const int gate = wid >> 1;          // 0=r, 1=z, 2=n
    const int sub  = wid & 1;
    const int col  = lane & 15;
    const int krow = lane >> 4;
    const int c_local = sub * 16 + col;               // 0..31
    const int g_glob  = gate * H_SZ + hs * HB + c_local;

    // B fragments: 16 K-tiles x half8 = 64 VGPR (R3/R5-proven resident size)
    half8 bfrag[16];
    {
        const f16* wp = wf16 + ((size_t)hs * GB + gate * HB + c_local) * H_SZ
                             + krow * 8;
        #pragma unroll
        for (int kk = 0; kk < 16; ++kk)
            bfrag[kk] = *reinterpret_cast<const half8*>(wp + kk * 32);
    }
    const float bias = b_hh[g_glob];

    // combine ownership (tid<256): batch row cb, col pair (cc, cc+1)
    const int cb = tid >> 4;
    const int cc = (tid & 15) * 2;
    float hm0 = 0.f, hm1 = 0.f;
    if (tid < 256) { hm0 = h0[hs * HB + cc]; hm1 = h0[hs * HB + cc + 1]; }

    const unsigned a_base = (unsigned)(col * 1024 + krow * 16);
    const unsigned a_swz  = ((unsigned)(col & 7)) << 4;

    // read granules (1024 x 16B over 384 threads; tid<256 has a third)
    const int i0 = tid, i1 = tid + NTHR, i2 = tid + 2 * NTHR;
    const bool has2 = (i2 < 1024);
    const f32x4 sentv = __builtin_bit_cast(f32x4,
        (uint32x4){SENT32, SENT32, SENT32, SENT32});

    const size_t phase_sz = (size_t)B_SZ * H_SZ;   // 65536 f16

    for (int t = 0; t < T_SEQ; ++t) {
        const int pc = t % 3;                // consume
        const int pn = (t + 1) % 3;          // produce
        const int pa = (t + 2) % 3;          // arm (fully consumed at poll-ok)
        const f16* hin = hbuf + (size_t)pc * phase_sz;
        f16* hnx = hbuf + (size_t)pn * phase_sz;
        f16* harm = hbuf + (size_t)pa * phase_sz;

        // gi load issued first (plain); drains with first poll wait
        f16x4 gv = load_f16x4_nw(
            gi + ((size_t)(t * NBS + bs) * G_SZ + g_glob) * MB + krow * 4);

        // ---- poll phase-pc granules until sentinel-free ----
        const f16* a0p = hin + (size_t)(bs * MB + (i0 >> 6)) * H_SZ + (i0 & 63) * 8;
        const f16* a1p = hin + (size_t)(bs * MB + (i1 >> 6)) * H_SZ + (i1 & 63) * 8;
        const f16* a2p = hin + (size_t)(bs * MB + (i2 >> 6)) * H_SZ + (i2 & 63) * 8;
        f32x4 v0 = cload_f4(a0p);
        f32x4 v1 = cload_f4(a1p);
        f32x4 v2;
        if (has2) v2 = cload_f4(a2p);
        wait_vm0();
        {
            int guard = 0;
            bool s0 = stale4(v0), s1 = stale4(v1), s2 = has2 && stale4(v2);
            while (__any(s0 | s1 | s2)) {
                if (s0) v0 = cload_f4((const void*)a0p);
                if (s1) v1 = cload_f4((const void*)a1p);
                if (s2) v2 = cload_f4((const void*)a2p);
                wait_vm0();
                s0 = stale4(v0); s1 = stale4(v1); s2 = has2 && stale4(v2);
                if (++guard > (1 << 20)) break;   // safety valve
            }
        }

        // ---- stage to LDS (swizzled); arm own granules of phase pa ----
        {
            unsigned l0 = ((unsigned)((i0 >> 6) * 1024 + (i0 & 63) * 16))
                          ^ (((unsigned)((i0 >> 6) & 7)) << 4);
            *reinterpret_cast<f32x4*>(h_lds + l0) = v0;
            unsigned l1 = ((unsigned)((i1 >> 6) * 1024 + (i1 & 63) * 16))
                          ^ (((unsigned)((i1 >> 6) & 7)) << 4);
            *reinterpret_cast<f32x4*>(h_lds + l1) = v1;
            if (has2) {
                unsigned l2 = ((unsigned)((i2 >> 6) * 1024 + (i2 & 63) * 16))
                              ^ (((unsigned)((i2 >> 6) & 7)) << 4);
                *reinterpret_cast<f32x4*>(h_lds + l2) = v2;
            }
            if (tid < 64) {   // our 64 granules: 16 rows x 4 granules of 8 cols
                int row = tid >> 2, g = tid & 3;
                cstore_f4(harm + (size_t)(bs * MB + row) * H_SZ + hs * HB + g * 8,
                          sentv);
            }
        }
        __syncthreads();

        // ---- gh: 16 batch x 16 cols, K=512 ----
        f32x4 acc = {0.f, 0.f, 0.f, 0.f};
        #pragma unroll
        for (int kk = 0; kk < 16; ++kk) {
            half8 av = *reinterpret_cast<const half8*>(
                h_lds + ((a_base + kk * 64) ^ a_swz));
            acc = __builtin_amdgcn_mfma_f32_16x16x32_f16(av, bfrag[kk], acc, 0, 0, 0);
        }
        wait_vm0();   // gi + arm stores retired (hidden under MFMA) [protocol-critical]

        // ---- per-gate activation to LDS ----
        if (gate == 0) {
            #pragma unroll
            for (int r = 0; r < 4; ++r)
                act_r[krow * 4 + r][c_local] =
                    1.f / (1.f + __expf(-(acc[r] + bias + (float)gv[r])));
        } else if (gate == 1) {
            #pragma unroll
            for (int r = 0; r < 4; ++r)
                act_z[krow * 4 + r][c_local] =
                    1.f / (1.f + __expf(-(acc[r] + bias + (float)gv[r])));
        } else {
            #pragma unroll
            for (int r = 0; r < 4; ++r) {
                act_n[krow * 4 + r][c_local] = acc[r] + bias;
                act_i[krow * 4 + r][c_local] = (float)gv[r];
            }
        }
        __syncthreads();

        // ---- combine (tid<256): write h ONCE to phase pn; out in background ----
        if (tid < 256) {
            float r0 = act_r[cb][cc],     r1 = act_r[cb][cc + 1];
            float z0 = act_z[cb][cc],     z1 = act_z[cb][cc + 1];
            float a0 = act_i[cb][cc]     + r0 * act_n[cb][cc];
            float a1 = act_i[cb][cc + 1] + r1 * act_n[cb][cc + 1];
            float n0 = 1.f - 2.f / (__expf(2.f * a0) + 1.f);
            float n1 = 1.f - 2.f / (__expf(2.f * a1) + 1.f);
            float hn0 = (1.f - z0) * n0 + z0 * hm0;
            float hn1 = (1.f - z1) * n1 + z1 * hm1;
            hn0 = fminf(fmaxf(hn0, -5.f), 5.f);
            hn1 = fminf(fmaxf(hn1, -5.f), 5.f);
            hm0 = hn0; hm1 = hn1;

            const int bg = bs * MB + cb;
            const int hg = hs * HB + cc;

            f16 p0 = (f16)hn0, p1 = (f16)hn1;
            unsigned pack = (unsigned)__builtin_bit_cast(unsigned short, p0)
                          | ((unsigned)__builtin_bit_cast(unsigned short, p1) << 16);
            cstore_u32(hnx + (size_t)bg * H_SZ + hg, pack);   // the publish

            *reinterpret_cast<float2*>(
                out + ((size_t)bg * T_SEQ + t) * H_SZ + hg) = make_float2(hn0, hn1);

            if (t == T_SEQ - 1)
                *reinterpret_cast<float2*>(
                    out + (size_t)B_SZ * T_SEQ * H_SZ + (size_t)bg * H_SZ + hg) =
                    make_float2(hn0, hn1);
        }
        // no drain, no flag, no barrier: next step's poll is the sync.
    }
}

// ---------------------------------------------------------------------------
extern "C" void kernel_launch(void* const* d_in, const int* in_sizes, int n_in,
                              void* d_out, int out_size, void* d_ws, size_t ws_size,
                              hipStream_t stream) {
    const float* x    = (const float*)d_in[0];
    const float* h0   = (const float*)d_in[1];
    const float* w_ih = (const float*)d_in[2];
    const float* w_hh = (const float*)d_in[3];
    const float* b_ih = (const float*)d_in[4];
    const float* b_hh = (const float*)d_in[5];
    float* out = (float*)d_out;

    char* p = (char*)d_ws;
    f16* wp16 = (f16*)p;   p += (size_t)I_SZ * G_SZ * 2;            // 768 KB
    f16* wf16 = (f16*)p;   p += (size_t)NHS * GB * H_SZ * 2;        // 1.5 MB
    f16* hbuf = (f16*)p;   p += (size_t)3 * B_SZ * H_SZ * 2;        // 384 KB
    f16* gi   = (f16*)p;   // [T][NBS][G][MB] f16 = 402 MB (ws >= 810 MB proven)

    setup_kernel<<<512, 256, 0, stream>>>(w_ih, w_hh, h0, wp16, wf16, hbuf);

    proj_kernel<<<T_SEQ * 4, 512, 0, stream>>>(x, wp16, b_ih, gi);

    gru_persist<<<NBS * NHS, NTHR, 0, stream>>>(gi, wf16, h0, b_hh, hbuf, out);
}